// Round 7
// baseline (90.512 us; speedup 1.0000x reference)
//
#include <hip/hip_runtime.h>

#define OUT_DIM 4096
#define IN_DIM 4096
#define NNZ 327680
#define BNNZ 2048
#define BATCH 512
#define CAP 160            // max nnz slots/row (mean 80, sigma ~9; P(>160)~1e-19; held rounds 1-6)
#define RT 16              // rows per block in spmm phase
#define NBLK 256
#define NTHR 1024

// LDS reused across phases (max 52 KB -> 2 blocks/CU possible, residency safe)
union SMem {
    struct { float tile[4][32][33]; } a;                       // transpose: 16.9 KB
    struct { int2 slot[RT][CAP]; float tile[RT][BATCH]; } b;   // spmm: 20 KB + 32 KB
};

// fp32 -> bf16 round-to-nearest-even
__device__ __forceinline__ unsigned short f2bf(float f) {
    unsigned int x = __float_as_uint(f);
    x += 0x7fffu + ((x >> 16) & 1u);
    return (unsigned short)(x >> 16);
}

__global__ __launch_bounds__(NTHR, 4)
void fused_k(const float* __restrict__ in,
             const int* __restrict__ w_rows, const int* __restrict__ w_cols,
             const float* __restrict__ w_vals,
             const int* __restrict__ b_idx, const float* __restrict__ b_vals,
             unsigned short* __restrict__ inputT, int2* __restrict__ slots,
             float* __restrict__ bias, int* __restrict__ counts,
             int* __restrict__ bar, float* __restrict__ out) {
    __shared__ SMem u;
    const int tid = threadIdx.x;
    const int bid = blockIdx.x;

    // ---- Phase A1: transpose [B,IN] f32 -> inputT [IN,B] bf16 -------------
    // 2048 32x32 tiles; block = 4 groups of 256 threads, 2 tiles per group.
    {
        const int g = tid >> 8, tx = tid & 31, ty = (tid >> 5) & 7;
        for (int rep = 0; rep < 2; ++rep) {
            const int job = rep * 1024 + bid * 4 + g;   // 0..2047
            const int bx = (job & 127) << 5;            // IN tile origin
            const int by = (job >> 7) << 5;             // B tile origin
            for (int i = ty; i < 32; i += 8)
                u.a.tile[g][i][tx] = in[(size_t)(by + i) * IN_DIM + bx + tx];
            __syncthreads();
            for (int i = ty; i < 32; i += 8)
                inputT[(size_t)(bx + i) * BATCH + by + tx] = f2bf(u.a.tile[g][tx][i]);
            __syncthreads();
        }
    }

    // ---- Phase A2: build per-row slot buckets (byte offsets) + bias -------
    {
        const int kbase = bid * (NNZ / NBLK);           // 1280 nnz per block
        for (int i = tid; i < NNZ / NBLK; i += NTHR) {
            const int k = kbase + i;
            const int r = w_rows[k];
            const int p = atomicAdd(&counts[r], 1);
            if (p < CAP)
                slots[(size_t)r * CAP + p] =
                    make_int2(w_cols[k] * (BATCH * 2), __float_as_int(w_vals[k]));
        }
        if (tid < BNNZ / NBLK) {                        // 8 bias entries per block
            const int k = bid * (BNNZ / NBLK) + tid;
            atomicAdd(&bias[b_idx[k]], b_vals[k]);
        }
    }

    // ---- Grid barrier (counter zeroed by the memset node each call) -------
    // All 256 blocks guaranteed co-resident: 16 waves/block, launch_bounds
    // gives >=2 blocks/CU capacity on 256 CUs.
    __syncthreads();
    if (tid == 0) {
        __threadfence();   // release: drain stores, write-back L2 (cross-XCD)
        __hip_atomic_fetch_add(bar, 1, __ATOMIC_RELEASE, __HIP_MEMORY_SCOPE_AGENT);
        while (__hip_atomic_load(bar, __ATOMIC_ACQUIRE, __HIP_MEMORY_SCOPE_AGENT) < NBLK)
            __builtin_amdgcn_s_sleep(8);
    }
    __syncthreads();

    // ---- Phase B: spmm (identical structure to round 6) -------------------
    const int w = tid >> 6;            // wave = row within block
    const int lane = tid & 63;         // lane = 8 batch elems
    const int r0 = bid * RT;
    const int r = r0 + w;

    const int cnt = min(counts[r], CAP);
    for (int i = lane; i < cnt; i += 64)
        u.b.slot[w][i] = slots[(size_t)r * CAP + i];
    // no barrier: wave-private slot rows

    const char* base = (const char*)inputT + lane * 16;

    float a0 = 0.f, a1 = 0.f, a2 = 0.f, a3 = 0.f;
    float a4 = 0.f, a5 = 0.f, a6 = 0.f, a7 = 0.f;
#pragma unroll 4
    for (int j = 0; j < cnt; ++j) {
        const int2 sv = u.b.slot[w][j];
        const uint4 q = *reinterpret_cast<const uint4*>(base + sv.x);
        const float v = __int_as_float(sv.y);
        a0 = fmaf(v, __uint_as_float(q.x << 16), a0);
        a1 = fmaf(v, __uint_as_float(q.x & 0xffff0000u), a1);
        a2 = fmaf(v, __uint_as_float(q.y << 16), a2);
        a3 = fmaf(v, __uint_as_float(q.y & 0xffff0000u), a3);
        a4 = fmaf(v, __uint_as_float(q.z << 16), a4);
        a5 = fmaf(v, __uint_as_float(q.z & 0xffff0000u), a5);
        a6 = fmaf(v, __uint_as_float(q.w << 16), a6);
        a7 = fmaf(v, __uint_as_float(q.w & 0xffff0000u), a7);
    }
    float4* tp = reinterpret_cast<float4*>(&u.b.tile[w][lane * 8]);
    tp[0] = make_float4(a0, a1, a2, a3);
    tp[1] = make_float4(a4, a5, a6, a7);
    __syncthreads();

    // store: thread t -> b = t/4 (+256*k2), r-quad = (t%4)*4; float4 along r
    const int rq = (tid & 3) * 4;
    const float4 bv = *reinterpret_cast<const float4*>(&bias[r0 + rq]);
#pragma unroll
    for (int k2 = 0; k2 < 2; ++k2) {
        const int b = (tid >> 2) + k2 * 256;
        float4 o = make_float4(u.b.tile[rq + 0][b] + bv.x, u.b.tile[rq + 1][b] + bv.y,
                               u.b.tile[rq + 2][b] + bv.z, u.b.tile[rq + 3][b] + bv.w);
        *reinterpret_cast<float4*>(&out[(size_t)b * OUT_DIM + r0 + rq]) = o;
    }
}

extern "C" void kernel_launch(void* const* d_in, const int* in_sizes, int n_in,
                              void* d_out, int out_size, void* d_ws, size_t ws_size,
                              hipStream_t stream) {
    const float* input   = (const float*)d_in[0];
    const int*   w_rows  = (const int*)d_in[1];
    const int*   w_cols  = (const int*)d_in[2];
    const float* w_vals  = (const float*)d_in[3];
    const int*   b_idx   = (const int*)d_in[4];
    const float* b_vals  = (const float*)d_in[5];
    float* out = (float*)d_out;

    char* ws = (char*)d_ws;
    const size_t MB = (size_t)1024 * 1024;
    unsigned short* inputT = (unsigned short*)ws;          // 4 MiB (bf16)
    int2*  slots  = (int2*)(ws + 4 * MB);                  // 4096*160*8 = 5 MiB
    char*  zbase  = ws + 9 * MB;                           // zeroed region:
    int*   bar    = (int*)zbase;                           //   [0,64): barrier
    float* bias   = (float*)(zbase + 64);                  //   16 KiB
    int*   counts = (int*)(zbase + 64 + 16 * 1024);        //   16 KiB

    // zero barrier + bias + counts (one small fill node)
    hipMemsetAsync(zbase, 0, 64 + 32 * 1024, stream);

    fused_k<<<NBLK, NTHR, 0, stream>>>(input, w_rows, w_cols, w_vals, b_idx, b_vals,
                                       inputT, slots, bias, counts, bar, out);
}

// Round 9
// 67.742 us; speedup vs baseline: 1.3361x; 1.3361x over previous
//
#include <hip/hip_runtime.h>

#define OUT_DIM 4096
#define IN_DIM 4096
#define NNZ 327680
#define BNNZ 2048
#define BATCH 512
#define CAP 160            // max nnz slots/row (mean 80, sigma ~9; P(>160)~1e-19; held rounds 1-7)
#define RT 8               // rows per spmm block

typedef int   i2 __attribute__((ext_vector_type(2)));
typedef float f4 __attribute__((ext_vector_type(4)));

// fp32 -> bf16 round-to-nearest-even
__device__ __forceinline__ unsigned short f2bf(float f) {
    unsigned int x = __float_as_uint(f);
    x += 0x7fffu + ((x >> 16) & 1u);
    return (unsigned short)(x >> 16);
}

// ---- transpose input [B, IN] fp32 -> inputT [IN, B] bf16; first 32 blocks ----
// ---- also zero the 8192-int region {bias[4096], counts[4096]}             ----
__global__ void transpose_k(const float* __restrict__ in,
                            unsigned short* __restrict__ outT,
                            int* __restrict__ zero_region) {
    const int bid = blockIdx.y * gridDim.x + blockIdx.x;
    const int tid = threadIdx.y * 32 + threadIdx.x;
    if (bid < 32) zero_region[bid * 256 + tid] = 0;

    __shared__ float tile[32][33];
    const int bx = blockIdx.x * 32;  // along IN
    const int by = blockIdx.y * 32;  // along B
    const int tx = threadIdx.x, ty = threadIdx.y;
    for (int i = ty; i < 32; i += 8)
        tile[i][tx] = in[(size_t)(by + i) * IN_DIM + bx + tx];
    __syncthreads();
    for (int i = ty; i < 32; i += 8)
        outT[(size_t)(bx + i) * BATCH + by + tx] = f2bf(tile[tx][i]);
}

// ------- build per-row slot buckets (byte offsets) + sparse-bias scatter ----
__global__ void build_k(const int* __restrict__ rows, const int* __restrict__ cols,
                        const float* __restrict__ vals, int* __restrict__ counts,
                        int2* __restrict__ slots,
                        const int* __restrict__ b_idx, const float* __restrict__ b_vals,
                        float* __restrict__ bias) {
    int k = blockIdx.x * blockDim.x + threadIdx.x;
    if (k < NNZ) {
        int r = rows[k];
        int p = atomicAdd(&counts[r], 1);
        if (p < CAP)   // byte offset into bf16 inputT row: col * BATCH * 2
            slots[(size_t)r * CAP + p] = make_int2(cols[k] * (BATCH * 2),
                                                   __float_as_int(vals[k]));
    }
    if (k < BNNZ) atomicAdd(&bias[b_idx[k]], b_vals[k]);
}

// --- SpMM: block = 8 rows x 512 b (512 thr); wave = 1 row, lane = 8 b ------
// launch_bounds(512,4): 64-VGPR budget -> 8-deep load pipeline (unroll 8).
// LDS 26 KB -> 2-4 blocks/CU -> up to 32 waves/CU.
__global__ __launch_bounds__(512, 4)
void spmm_k(const unsigned short* __restrict__ inputT, const int* __restrict__ counts,
            const int2* __restrict__ slots, const float* __restrict__ bias,
            float* __restrict__ out) {
    const int w = threadIdx.x >> 6;      // wave = row within block
    const int lane = threadIdx.x & 63;   // lane = 8 batch elems
    const int r0 = blockIdx.x * RT;
    const int r = r0 + w;

    __shared__ int2  s_slot[RT][CAP];    // 10 KB, wave-private
    __shared__ float tile[RT][BATCH];    // 16 KB

    const int cnt = min(counts[r], CAP);
    for (int i = lane; i < cnt; i += 64) {
        i2 sv = __builtin_nontemporal_load(
            reinterpret_cast<const i2*>(&slots[(size_t)r * CAP + i]));
        s_slot[w][i] = make_int2(sv.x, sv.y);
    }
    // no barrier: wave-private slot rows

    const char* base = (const char*)inputT + lane * 16;

    float a0 = 0.f, a1 = 0.f, a2 = 0.f, a3 = 0.f;
    float a4 = 0.f, a5 = 0.f, a6 = 0.f, a7 = 0.f;
#pragma unroll 8
    for (int j = 0; j < cnt; ++j) {
        const int2 sv = s_slot[w][j];
        const uint4 q = *reinterpret_cast<const uint4*>(base + sv.x);
        const float v = __int_as_float(sv.y);
        a0 = fmaf(v, __uint_as_float(q.x << 16), a0);
        a1 = fmaf(v, __uint_as_float(q.x & 0xffff0000u), a1);
        a2 = fmaf(v, __uint_as_float(q.y << 16), a2);
        a3 = fmaf(v, __uint_as_float(q.y & 0xffff0000u), a3);
        a4 = fmaf(v, __uint_as_float(q.z << 16), a4);
        a5 = fmaf(v, __uint_as_float(q.z & 0xffff0000u), a5);
        a6 = fmaf(v, __uint_as_float(q.w << 16), a6);
        a7 = fmaf(v, __uint_as_float(q.w & 0xffff0000u), a7);
    }
    float4* tp = reinterpret_cast<float4*>(&tile[w][lane * 8]);
    tp[0] = make_float4(a0, a1, a2, a3);
    tp[1] = make_float4(a4, a5, a6, a7);
    __syncthreads();

    // store: thread t -> b = t/2 (+256*k2), r-quad = (t%2)*4; float4 along r.
    // Thread pairs cover 32 B; adjacent blocks complete each 64 B line.
    const int rq = (threadIdx.x & 1) * 4;
    const float4 bv = *reinterpret_cast<const float4*>(&bias[r0 + rq]);
#pragma unroll
    for (int k2 = 0; k2 < 2; ++k2) {
        const int b = (threadIdx.x >> 1) + k2 * 256;
        f4 o = {tile[rq + 0][b] + bv.x, tile[rq + 1][b] + bv.y,
                tile[rq + 2][b] + bv.z, tile[rq + 3][b] + bv.w};
        __builtin_nontemporal_store(o, reinterpret_cast<f4*>(
            &out[(size_t)b * OUT_DIM + r0 + rq]));
    }
}

extern "C" void kernel_launch(void* const* d_in, const int* in_sizes, int n_in,
                              void* d_out, int out_size, void* d_ws, size_t ws_size,
                              hipStream_t stream) {
    const float* input   = (const float*)d_in[0];
    const int*   w_rows  = (const int*)d_in[1];
    const int*   w_cols  = (const int*)d_in[2];
    const float* w_vals  = (const float*)d_in[3];
    const int*   b_idx   = (const int*)d_in[4];
    const float* b_vals  = (const float*)d_in[5];
    float* out = (float*)d_out;

    char* ws = (char*)d_ws;
    const size_t MB = (size_t)1024 * 1024;
    unsigned short* inputT = (unsigned short*)ws;      // 4 MiB (bf16)
    float* bias   = (float*)(ws + 4 * MB);             // 16 KiB
    int*   counts = (int*)(ws + 4 * MB + 16 * 1024);   // 16 KiB
    int2*  slots  = (int2*)(ws + 4 * MB + 32 * 1024);  // 4096*160*8 = 5 MiB

    dim3 tb(32, 8);
    // zero_region = {bias, counts} contiguous 8192 ints, zeroed by first 32 blocks
    transpose_k<<<dim3(IN_DIM / 32, BATCH / 32), tb, 0, stream>>>(input, inputT,
                                                                  (int*)bias);

    build_k<<<(NNZ + 255) / 256, 256, 0, stream>>>(w_rows, w_cols, w_vals, counts,
                                                   slots, b_idx, b_vals, bias);

    spmm_k<<<OUT_DIM / RT, 512, 0, stream>>>(inputT, counts, slots, bias, out);
}

// Round 10
// 59.103 us; speedup vs baseline: 1.5314x; 1.1462x over previous
//
#include <hip/hip_runtime.h>

#define OUT_DIM 4096
#define IN_DIM 4096
#define NNZ 327680
#define BNNZ 2048
#define BATCH 512
#define CAP 160            // max nnz slots/row (mean 80, sigma ~9; P(>160)~1e-19; held rounds 1-9)
#define RT 16              // rows per spmm block
#define PF 8               // load-pipeline depth (uint4 x8 = 32 VGPR in flight)

// fp32 -> bf16 round-to-nearest-even
__device__ __forceinline__ unsigned short f2bf(float f) {
    unsigned int x = __float_as_uint(f);
    x += 0x7fffu + ((x >> 16) & 1u);
    return (unsigned short)(x >> 16);
}

// ---- transpose input [B, IN] fp32 -> inputT [IN, B] bf16; first 32 blocks ----
// ---- also zero the 8192-int region {bias[4096], counts[4096]}             ----
__global__ void transpose_k(const float* __restrict__ in,
                            unsigned short* __restrict__ outT,
                            int* __restrict__ zero_region) {
    const int bid = blockIdx.y * gridDim.x + blockIdx.x;
    const int tid = threadIdx.y * 32 + threadIdx.x;
    if (bid < 32) zero_region[bid * 256 + tid] = 0;

    __shared__ float tile[32][33];
    const int bx = blockIdx.x * 32;  // along IN
    const int by = blockIdx.y * 32;  // along B
    const int tx = threadIdx.x, ty = threadIdx.y;
    for (int i = ty; i < 32; i += 8)
        tile[i][tx] = in[(size_t)(by + i) * IN_DIM + bx + tx];
    __syncthreads();
    for (int i = ty; i < 32; i += 8)
        outT[(size_t)(bx + i) * BATCH + by + tx] = f2bf(tile[tx][i]);
}

// ------- build per-row slot buckets (byte offsets) + sparse-bias scatter ----
__global__ void build_k(const int* __restrict__ rows, const int* __restrict__ cols,
                        const float* __restrict__ vals, int* __restrict__ counts,
                        int2* __restrict__ slots,
                        const int* __restrict__ b_idx, const float* __restrict__ b_vals,
                        float* __restrict__ bias) {
    int k = blockIdx.x * blockDim.x + threadIdx.x;
    if (k < NNZ) {
        int r = rows[k];
        int p = atomicAdd(&counts[r], 1);
        if (p < CAP)   // byte offset into bf16 inputT row: col * BATCH * 2
            slots[(size_t)r * CAP + p] = make_int2(cols[k] * (BATCH * 2),
                                                   __float_as_int(vals[k]));
    }
    if (k < BNNZ) atomicAdd(&bias[b_idx[k]], b_vals[k]);
}

// --- SpMM: block = 16 rows x 512 b (1024 thr); wave = 1 row, lane = 8 b ----
// Inner loop: explicit PF-deep register-rotated load pipeline (static idx),
// slot list zero-padded so no guards needed. launch_bounds(1024,4) -> 128
// VGPR budget so q[PF] stays resident (round 6/7's (.,8) capped at 28 VGPR,
// serializing every gather: VALUBusy 10.9%, MLP~2).
__global__ __launch_bounds__(1024, 4)
void spmm_k(const unsigned short* __restrict__ inputT, const int* __restrict__ counts,
            const int2* __restrict__ slots, const float* __restrict__ bias,
            float* __restrict__ out) {
    const int w = threadIdx.x >> 6;      // wave = row within block
    const int lane = threadIdx.x & 63;   // lane = 8 batch elems
    const int r0 = blockIdx.x * RT;
    const int r = r0 + w;

    __shared__ int2  s_slot[RT][CAP + PF];   // 21 KB, wave-private rows
    __shared__ float tile[RT][BATCH];        // 32 KB

    const int cnt = min(counts[r], CAP);
    const int cntp = max(PF, (cnt + PF - 1) & ~(PF - 1));   // padded trip count
    for (int i = lane; i < cntp + PF; i += 64) {
        int2 sv = (i < cnt) ? slots[(size_t)r * CAP + i] : make_int2(0, 0);
        s_slot[w][i] = sv;   // zero-pad: offset 0 (valid), val 0.0f (no-op fma)
    }
    // no barrier: wave-private slot rows

    const char* base = (const char*)inputT + lane * 16;

    float a0 = 0.f, a1 = 0.f, a2 = 0.f, a3 = 0.f;
    float a4 = 0.f, a5 = 0.f, a6 = 0.f, a7 = 0.f;

    uint4 q[PF];
    float vv[PF];
#pragma unroll
    for (int k = 0; k < PF; ++k) {
        const int2 sv = s_slot[w][k];
        vv[k] = __int_as_float(sv.y);
        q[k] = *reinterpret_cast<const uint4*>(base + sv.x);
    }
    for (int j = 0; j < cntp; j += PF) {
#pragma unroll
        for (int k = 0; k < PF; ++k) {
            const uint4 qq = q[k];
            const float v = vv[k];
            const int2 sv = s_slot[w][j + PF + k];   // pad makes this always valid
            vv[k] = __int_as_float(sv.y);
            q[k] = *reinterpret_cast<const uint4*>(base + sv.x);
            a0 = fmaf(v, __uint_as_float(qq.x << 16), a0);
            a1 = fmaf(v, __uint_as_float(qq.x & 0xffff0000u), a1);
            a2 = fmaf(v, __uint_as_float(qq.y << 16), a2);
            a3 = fmaf(v, __uint_as_float(qq.y & 0xffff0000u), a3);
            a4 = fmaf(v, __uint_as_float(qq.z << 16), a4);
            a5 = fmaf(v, __uint_as_float(qq.z & 0xffff0000u), a5);
            a6 = fmaf(v, __uint_as_float(qq.w << 16), a6);
            a7 = fmaf(v, __uint_as_float(qq.w & 0xffff0000u), a7);
        }
    }

    float4* tp = reinterpret_cast<float4*>(&tile[w][lane * 8]);
    tp[0] = make_float4(a0, a1, a2, a3);
    tp[1] = make_float4(a4, a5, a6, a7);
    __syncthreads();

    // store: thread t -> b = t/4 (+256*k2), r-quad = (t%4)*4; float4 along r.
    // 4-thread groups cover the full 64B line [r0, r0+16) -> line-coalesced.
    const int rq = (threadIdx.x & 3) * 4;
    const float4 bv = *reinterpret_cast<const float4*>(&bias[r0 + rq]);
#pragma unroll
    for (int k2 = 0; k2 < 2; ++k2) {
        const int b = (threadIdx.x >> 2) + k2 * 256;
        float4 o = make_float4(tile[rq + 0][b] + bv.x, tile[rq + 1][b] + bv.y,
                               tile[rq + 2][b] + bv.z, tile[rq + 3][b] + bv.w);
        *reinterpret_cast<float4*>(&out[(size_t)b * OUT_DIM + r0 + rq]) = o;
    }
}

extern "C" void kernel_launch(void* const* d_in, const int* in_sizes, int n_in,
                              void* d_out, int out_size, void* d_ws, size_t ws_size,
                              hipStream_t stream) {
    const float* input   = (const float*)d_in[0];
    const int*   w_rows  = (const int*)d_in[1];
    const int*   w_cols  = (const int*)d_in[2];
    const float* w_vals  = (const float*)d_in[3];
    const int*   b_idx   = (const int*)d_in[4];
    const float* b_vals  = (const float*)d_in[5];
    float* out = (float*)d_out;

    char* ws = (char*)d_ws;
    const size_t MB = (size_t)1024 * 1024;
    unsigned short* inputT = (unsigned short*)ws;      // 4 MiB (bf16)
    float* bias   = (float*)(ws + 4 * MB);             // 16 KiB
    int*   counts = (int*)(ws + 4 * MB + 16 * 1024);   // 16 KiB
    int2*  slots  = (int2*)(ws + 4 * MB + 32 * 1024);  // 4096*160*8 = 5 MiB

    dim3 tb(32, 8);
    // zero_region = {bias, counts} contiguous 8192 ints, zeroed by first 32 blocks
    transpose_k<<<dim3(IN_DIM / 32, BATCH / 32), tb, 0, stream>>>(input, inputT,
                                                                  (int*)bias);

    build_k<<<(NNZ + 255) / 256, 256, 0, stream>>>(w_rows, w_cols, w_vals, counts,
                                                   slots, b_idx, b_vals, bias);

    spmm_k<<<OUT_DIM / RT, 1024, 0, stream>>>(inputT, counts, slots, bias, out);
}